// Round 3
// baseline (205.556 us; speedup 1.0000x reference)
//
#include <hip/hip_runtime.h>

// TenHotEncodeLayer: out[n, x[n,j]] = 1.0, rest zeros.
// B=8192 rows, NUM_TOKENS=32000 cols (f32), K=10 indices/row.
//
// Persistent-block streaming: 2048 blocks (8/CU), each owns 4 consecutive
// rows (512 KB contiguous). Indices for all 4 rows preloaded once per block
// (wave-uniform -> scalar loads), so the load-latency bubble is paid once
// per 512 KB instead of once per 128 KB, and there are 4x fewer block
// launch/retire boundaries. Mimics fillBufferAligned's persistent regime
// (measured 6.87 TB/s on this chip).

#define NUM_TOKENS 32000
#define KHOT 10
#define F4_PER_ROW (NUM_TOKENS / 4)   // 8000 float4 per row (128,000 B)
#define BLOCK 256
#define ROWS_PER_BLOCK 4

__global__ __launch_bounds__(BLOCK) void TenHotEncodeLayer_53566832115799_kernel(
    const int* __restrict__ x, float* __restrict__ out, int B) {
    const int row0 = blockIdx.x * ROWS_PER_BLOCK;

    // Preload ALL indices for this block's rows. Addresses are wave-uniform
    // (row0 uniform, r/j unrolled) -> scalar loads, one latency bubble total.
    int      c[ROWS_PER_BLOCK][KHOT];   // owning float4-chunk (-1 = dropped)
    unsigned bit[ROWS_PER_BLOCK][KHOT]; // element bit within chunk
    #pragma unroll
    for (int r = 0; r < ROWS_PER_BLOCK; ++r) {
        const int row = row0 + r;
        #pragma unroll
        for (int j = 0; j < KHOT; ++j) {
            const int idx = (row < B) ? x[row * KHOT + j] : -1;
            const bool ok = (idx >= 0) && (idx < NUM_TOKENS);
            c[r][j]   = ok ? (idx >> 2) : -1;   // -1 never matches a chunk id
            bit[r][j] = 1u << (idx & 3);
        }
    }

    #pragma unroll
    for (int r = 0; r < ROWS_PER_BLOCK; ++r) {
        const int row = row0 + r;
        if (row >= B) break;
        float4* __restrict__ rowp =
            reinterpret_cast<float4*>(out) + (size_t)row * F4_PER_ROW;
        for (int i = threadIdx.x; i < F4_PER_ROW; i += BLOCK) {
            unsigned m = 0u;
            #pragma unroll
            for (int j = 0; j < KHOT; ++j) {
                m |= (c[r][j] == i) ? bit[r][j] : 0u;  // dup indices OR same bit
            }
            float4 v;
            v.x = (m & 1u) ? 1.0f : 0.0f;
            v.y = (m & 2u) ? 1.0f : 0.0f;
            v.z = (m & 4u) ? 1.0f : 0.0f;
            v.w = (m & 8u) ? 1.0f : 0.0f;
            rowp[i] = v;   // coalesced 16 B/lane streaming store
        }
    }
}

extern "C" void kernel_launch(void* const* d_in, const int* in_sizes, int n_in,
                              void* d_out, int out_size, void* d_ws, size_t ws_size,
                              hipStream_t stream) {
    const int* x = (const int*)d_in[0];
    float* out = (float*)d_out;
    const int B = in_sizes[0] / KHOT;  // 8192
    const int grid = (B + ROWS_PER_BLOCK - 1) / ROWS_PER_BLOCK;  // 2048
    TenHotEncodeLayer_53566832115799_kernel<<<grid, BLOCK, 0, stream>>>(x, out, B);
}

// Round 5
// 203.480 us; speedup vs baseline: 1.0102x; 1.0102x over previous
//
#include <hip/hip_runtime.h>

// TenHotEncodeLayer: out[n, x[n,j]] = 1.0, rest zeros.
// B=8192 rows, NUM_TOKENS=32000 cols (f32), K=10 indices/row.
//
// R5 = R4 with the compile fix: __builtin_nontemporal_store requires a
// native clang vector type, not HIP_vector_type<float,4>. Use
// ext_vector_type(4) float -> emits global_store_dwordx4 ... nt.
// Theory under test: plain stores write-allocate in L2 (32MB) and the 1GB
// stream is gated by dirty-eviction; nt stores bypass L2 allocation and
// should approach fillBufferAligned's proven 6.87 TB/s.

#define NUM_TOKENS 32000
#define KHOT 10
#define F4_PER_ROW (NUM_TOKENS / 4)   // 8000 float4 per row (128,000 B)
#define BLOCK 256

typedef float f32x4 __attribute__((ext_vector_type(4)));

__global__ __launch_bounds__(BLOCK) void TenHotEncodeLayer_53566832115799_kernel(
    const int* __restrict__ x, float* __restrict__ out) {
    const int row = blockIdx.x;

    // Preload this row's 10 indices (wave-uniform addresses -> scalar loads).
    int      c[KHOT];    // owning float4-chunk of index j (-1 if dropped)
    unsigned bit[KHOT];  // element bit within the chunk
    #pragma unroll
    for (int j = 0; j < KHOT; ++j) {
        const int idx = x[row * KHOT + j];
        const bool ok = (idx >= 0) && (idx < NUM_TOKENS);
        c[j]   = ok ? (idx >> 2) : -1;   // -1 never matches a chunk id
        bit[j] = 1u << (idx & 3);
    }

    f32x4* __restrict__ rowp = reinterpret_cast<f32x4*>(out) + (size_t)row * F4_PER_ROW;

    // Unroll-by-2: two independent nt stores in flight per iteration.
    #pragma unroll 1
    for (int i0 = threadIdx.x; i0 < F4_PER_ROW; i0 += 2 * BLOCK) {
        #pragma unroll
        for (int u = 0; u < 2; ++u) {
            const int i = i0 + u * BLOCK;
            if (i < F4_PER_ROW) {
                unsigned m = 0u;
                #pragma unroll
                for (int j = 0; j < KHOT; ++j) {
                    m |= (c[j] == i) ? bit[j] : 0u;  // dup indices OR same bit
                }
                f32x4 v;
                v.x = (m & 1u) ? 1.0f : 0.0f;
                v.y = (m & 2u) ? 1.0f : 0.0f;
                v.z = (m & 4u) ? 1.0f : 0.0f;
                v.w = (m & 8u) ? 1.0f : 0.0f;
                __builtin_nontemporal_store(v, &rowp[i]);  // streaming 16B nt store
            }
        }
    }
}

extern "C" void kernel_launch(void* const* d_in, const int* in_sizes, int n_in,
                              void* d_out, int out_size, void* d_ws, size_t ws_size,
                              hipStream_t stream) {
    const int* x = (const int*)d_in[0];
    float* out = (float*)d_out;
    const int B = in_sizes[0] / KHOT;  // 8192
    TenHotEncodeLayer_53566832115799_kernel<<<B, BLOCK, 0, stream>>>(x, out);
}